// Round 12
// baseline (146.035 us; speedup 1.0000x reference)
//
#include <hip/hip_runtime.h>
#include <math.h>

#define L_IN 256000
#define T_FR 1601
#define T_PAD 1616
#define NMEL_K 64
#define F_BINS 257
#define HOP_K 160
#define PRE_E 0.97f
#define LOG_GUARD_K 5.9604644775390625e-08f  // 2^-24
#define FPB 8         // frames per block (r12: 16->8 for block-level TLP)
#define CONC 4        // waves per block (r10 lesson: 512-thr caps VGPR@44)
#define GROUPS 201    // ceil(1601/8)
#define SPAN 1632     // 160*(FPB-1) + 512

typedef int v2i __attribute__((ext_vector_type(2)));

__device__ __forceinline__ float2 cmulf(float2 a, float2 b) {
  return make_float2(a.x * b.x - a.y * b.y, a.x * b.y + a.y * b.x);
}

// quad_perm DPP lane exchanges (VALU pipe — no DS cost).
__device__ __forceinline__ float dpp_xor1(float x) {
  return __int_as_float(__builtin_amdgcn_mov_dpp(__float_as_int(x), 0xB1, 0xF, 0xF, true));
}
__device__ __forceinline__ float dpp_xor2(float x) {
  return __int_as_float(__builtin_amdgcn_mov_dpp(__float_as_int(x), 0x4E, 0xF, 0xF, true));
}
// row_ror:8 == xor8 exchange. Verified exact in r6.
__device__ __forceinline__ float dpp_ror8(float x) {
  return __int_as_float(__builtin_amdgcn_mov_dpp(__float_as_int(x), 0x128, 0xF, 0xF, true));
}
// xor4 = row_half_mirror (0x141) then quad mirror (0x1B). Verified exact in r9.
__device__ __forceinline__ float dpp_hmir(float x) {
  return __int_as_float(__builtin_amdgcn_mov_dpp(__float_as_int(x), 0x141, 0xF, 0xF, true));
}
__device__ __forceinline__ float dpp_qmir(float x) {
  return __int_as_float(__builtin_amdgcn_mov_dpp(__float_as_int(x), 0x1B, 0xF, 0xF, true));
}
__device__ __forceinline__ float dpp_xor4(float x) { return dpp_qmir(dpp_hmir(x)); }

// gfx950 permlane swaps via the BUILTIN. Verified exact in r8.
__device__ __forceinline__ void lane_swap32(float v, float& lo, float& hi) {
  v2i r = __builtin_amdgcn_permlane32_swap(__float_as_int(v), __float_as_int(v),
                                           false, false);
  lo = __int_as_float(r.x);
  hi = __int_as_float(r.y);
}
__device__ __forceinline__ void lane_swap16(float v, float& lo, float& hi) {
  v2i r = __builtin_amdgcn_permlane16_swap(__float_as_int(v), __float_as_int(v),
                                           false, false);
  lo = __int_as_float(r.x);
  hi = __int_as_float(r.y);
}

// pw quad-slot swizzle. Verified r2..r11: conflicts 3.83M -> 1.19M, neutral math.
#define PW_SWZ(q) ((q) ^ (((q) >> 3) & 7))

// Prep: per-mel compact filterbank + aligned lo, and zero the stats accumulators.
__global__ void prep_kernel(const float* __restrict__ fb, float* __restrict__ fbc,
                            int* __restrict__ loAl, float* __restrict__ rsum,
                            float* __restrict__ rsumsq) {
  const int m = blockIdx.x;
  const int t = threadIdx.x;
  if (t < 32) {
    rsum[m * 32 + t] = 0.0f;
    rsumsq[m * 32 + t] = 0.0f;
  }
  int first = 512, last = -1;
  for (int c = 0; c < 5; ++c) {
    int f = t + 64 * c;
    if (f < F_BINS) {
      float v = fb[m * F_BINS + f];
      if (v > 0.0f) { first = min(first, f); last = max(last, f); }
    }
  }
  for (int off = 32; off > 0; off >>= 1) {
    first = min(first, __shfl_xor(first, off));
    last = max(last, __shfl_xor(last, off));
  }
  int lo = (first <= last) ? first : 0;
  int lastv = (first <= last) ? last : 0;
  int la = lo & ~3;
  if (t == 0) loAl[m] = la;
  if (t < 32) {
    int f = la + t;
    float v = (f >= lo && f <= lastv && f < F_BINS) ? fb[m * F_BINS + f] : 0.0f;
    fbc[m * 32 + t] = v;
  }
}

// r11: sign-injected branch-free butterfly (verified): sg = hi?-1:+1,
// (wc,ws) = hi?twiddle:(1,0); u = fma(B,sg,t); out = u*W.
#define FFT_STAGE_X(I, PR, PI)                                 \
  {                                                            \
    const float sg__ = sgf[I], wc__ = wcv[I], ws__ = wsv[I];   \
    _Pragma("unroll")                                          \
    for (int r = 0; r < 4; ++r) {                              \
      float tr = (PR), ti = (PI);                              \
      float ur = fmaf(Br[r], sg__, tr);                        \
      float ui = fmaf(Bi[r], sg__, ti);                        \
      Br[r] = fmaf(-ws__, ui, ur * wc__);                      \
      Bi[r] = fmaf(ws__, ur, ui * wc__);                       \
    }                                                          \
  }

// Swap-based variant (stages H=32,16): u = fma(hi_val, sg, lo_val).
#define FFT_STAGE_XS(I, SWAPFN)                                \
  {                                                            \
    const float sg__ = sgf[I], wc__ = wcv[I], ws__ = wsv[I];   \
    _Pragma("unroll")                                          \
    for (int r = 0; r < 4; ++r) {                              \
      float lor, hir, loi, hii;                                \
      SWAPFN(Br[r], lor, hir);                                 \
      SWAPFN(Bi[r], loi, hii);                                 \
      float ur = fmaf(hir, sg__, lor);                         \
      float ui = fmaf(hii, sg__, loi);                         \
      Br[r] = fmaf(-ws__, ui, ur * wc__);                      \
      Bi[r] = fmaf(ws__, ur, ui * wc__);                       \
    }                                                          \
  }

// K1: 256 threads = 4 waves, 8 frames per block, 2 sequential frames per wave.
// r12: halve block work (FPB 16->8) to double resident independent blocks at
// UNCHANGED per-wave code/VGPR — r8/r9/r11 proved op cuts are off the critical
// path; stalls need more concurrent chains (r10's 512-thr TLP failed only via
// its VGPR cap). LDS 13.4 KB -> ~8 blocks/CU residency possible.
__global__ void __launch_bounds__(256) frame_fft_mel_kernel(
    const float* __restrict__ x, const int* __restrict__ seq_len,
    const float* __restrict__ window, const float* __restrict__ fbc,
    const int* __restrict__ loAl, float* __restrict__ out,
    float* __restrict__ rsum, float* __restrict__ rsumsq) {
  __shared__ __align__(16) float xs[SPAN];
  __shared__ __align__(16) float pw[CONC][288];
  __shared__ float outm[NMEL_K][FPB + 1];

  const int tid = threadIdx.x;
  const int w = tid >> 6;
  const int lane = tid & 63;
  const int b = blockIdx.x / GROUPS;
  const int g = blockIdx.x - b * GROUPS;
  const int t0 = g * FPB;
  const float* xb = x + (size_t)b * L_IN;
  const int base = t0 * HOP_K - 256;
  const int fl = seq_len[b] / HOP_K + 1;

  // stage input span: preemph (+ reflect on edge blocks)
  if (base >= 0 && base + SPAN <= L_IN) {
    // fast path: float4 interior (base = 1280g-256, multiple of 4 for g>0)
    const float4* xb4 = (const float4*)(xb + base);
    float4* xs4 = (float4*)xs;
    for (int s4 = tid; s4 < SPAN / 4; s4 += 256) {
      float4 cur = xb4[s4];
      float prev = xb[base + 4 * s4 - 1];
      float4 o;
      o.x = fmaf(-PRE_E, prev, cur.x);
      o.y = fmaf(-PRE_E, cur.x, cur.y);
      o.z = fmaf(-PRE_E, cur.y, cur.z);
      o.w = fmaf(-PRE_E, cur.z, cur.w);
      xs4[s4] = o;
    }
  } else {
    for (int n = tid; n < SPAN; n += 256) {
      int i = base + n;
      i = (i < 0) ? -i : i;
      i = (i >= L_IN) ? (2 * L_IN - 2 - i) : i;
      xs[n] = (i == 0) ? xb[0] : fmaf(-PRE_E, xb[i - 1], xb[i]);
    }
  }

  // zero pw tail once (gather overrun region 257..287 — never overwritten)
  if (lane >= 33 && lane < 64) pw[w][224 + lane] = 0.0f;  // 257..287

  // ---- per-lane frame-invariant constants (all hoisted) ----
  const int sig = __builtin_bitreverse32(lane) >> 26;  // bitrev6(lane)
  float wr[4], wi[4];
#pragma unroll
  for (int q = 0; q < 4; ++q) {
    float2 wv = *(const float2*)(window + 2 * (lane + 64 * q));
    wr[q] = wv.x; wi[q] = wv.y;
  }
  float2 tw1, tw2, tw3;  // W256^(l*r)
  {
    float a = -0.024543692606170259f * (float)lane;  // -2*pi/256
    __sincosf(a, &tw1.y, &tw1.x);
    tw2 = cmulf(tw1, tw1);
    tw3 = cmulf(tw2, tw1);
  }
  // per-lane stage constants — sign + selected twiddle (lo lanes: (1,0)).
  float wcv[6], wsv[6], sgf[6];
#pragma unroll
  for (int i = 0; i < 6; ++i) {
    int H = 32 >> i;
    bool hi = (lane & H) != 0;
    int p = lane & (H - 1);
    float a = -3.14159265358979323846f * (float)p / (float)H;
    float s, c;
    __sincosf(a, &s, &c);
    wcv[i] = hi ? c : 1.0f;
    wsv[i] = hi ? s : 0.0f;
    sgf[i] = hi ? -1.0f : 1.0f;
  }
  float cu[4], su[4];  // unpack twiddle e^{-i*pi*(4*sig+r)/256}
  {
    float a = -0.049087385212340519f * (float)sig;  // -pi/64
    float cb, sb;
    __sincosf(a, &sb, &cb);
    const float C[4] = {1.0f, 0.99992470183914454f, 0.99969881869620425f, 0.99932238458834954f};
    const float S[4] = {0.0f, 0.01227153828571993f, 0.02454122852291229f, 0.03680722294135883f};
#pragma unroll
    for (int r = 0; r < 4; ++r) {
      cu[r] = cb * C[r] + sb * S[r];
      su[r] = sb * C[r] - cb * S[r];
    }
  }
  const int idx0 = __builtin_bitreverse32((64 - sig) & 63) >> 26;  // lane of Y0[(64-s)&63]
  const int la = loAl[lane];
  const float4* fr4 = (const float4*)fbc + lane * 8;
  const int sigswz = PW_SWZ(sig);  // hoisted swizzled write slot

  __syncthreads();

  float sm = 0.0f, ssq = 0.0f;  // per-(b, mel=lane) stats partials

  for (int c = 0; c < FPB / CONC; ++c) {
    const int j = c * CONC + w;
    const int off = j * HOP_K;

    float Br[4], Bi[4];
    {
      float zr[4], zi[4];
#pragma unroll
      for (int q = 0; q < 4; ++q) {
        float2 v = *(const float2*)(xs + off + 2 * (lane + 64 * q));
        zr[q] = v.x * wr[q];
        zi[q] = v.y * wi[q];
      }
      // FFT_4 over q (W4 = -i), then W256^{l*r} twiddle
      float e0r = zr[0] + zr[2], e0i = zi[0] + zi[2];
      float e1r = zr[1] + zr[3], e1i = zi[1] + zi[3];
      float d0r = zr[0] - zr[2], d0i = zi[0] - zi[2];
      float d1r = zr[1] - zr[3], d1i = zi[1] - zi[3];
      Br[0] = e0r + e1r; Bi[0] = e0i + e1i;
      float A2r = e0r - e1r, A2i = e0i - e1i;
      float A1r = d0r + d1i, A1i = d0i - d1r;
      float A3r = d0r - d1i, A3i = d0i + d1r;
      Br[1] = A1r * tw1.x - A1i * tw1.y; Bi[1] = A1r * tw1.y + A1i * tw1.x;
      Br[2] = A2r * tw2.x - A2i * tw2.y; Bi[2] = A2r * tw2.y + A2i * tw2.x;
      Br[3] = A3r * tw3.x - A3i * tw3.y; Bi[3] = A3r * tw3.y + A3i * tw3.x;
    }

    // FFT_64 across lanes: 6 DIF radix-2 stages, all VALU, all branch-free.
    FFT_STAGE_XS(0, lane_swap32);
    FFT_STAGE_XS(1, lane_swap16);
    FFT_STAGE_X(2, dpp_ror8(Br[r]), dpp_ror8(Bi[r]));
    FFT_STAGE_X(3, dpp_xor4(Br[r]), dpp_xor4(Bi[r]));
    FFT_STAGE_X(4, dpp_xor2(Br[r]), dpp_xor2(Bi[r]));
    // stage H=1: W = 1 identically — just the sign-injected add
    {
      const float sg5 = sgf[5];
#pragma unroll
      for (int r = 0; r < 4; ++r) {
        float tr = dpp_xor1(Br[r]), ti = dpp_xor1(Bi[r]);
        Br[r] = fmaf(Br[r], sg5, tr);
        Bi[r] = fmaf(Bi[r], sg5, ti);
      }
    }

    // packed-real unpack + power spectrum (k = 4*sig + r)
    {
      float q3r = __shfl_xor(Br[3], 63), q3i = __shfl_xor(Bi[3], 63);
      float q2r = __shfl_xor(Br[2], 63), q2i = __shfl_xor(Bi[2], 63);
      float q1r = __shfl_xor(Br[1], 63), q1i = __shfl_xor(Bi[1], 63);
      float q0r = __shfl(Br[0], idx0), q0i = __shfl(Bi[0], idx0);
      float qr[4] = {q0r, q3r, q2r, q1r};
      float qi_[4] = {q0i, q3i, q2i, q1i};
      float pv[4];
#pragma unroll
      for (int r = 0; r < 4; ++r) {
        float Er = 0.5f * (Br[r] + qr[r]);
        float Ei = 0.5f * (Bi[r] - qi_[r]);
        float Or = 0.5f * (Bi[r] + qi_[r]);
        float Oi = 0.5f * (qr[r] - Br[r]);
        float Xr = Er + cu[r] * Or - su[r] * Oi;
        float Xi = Ei + cu[r] * Oi + su[r] * Or;
        pv[r] = Xr * Xr + Xi * Xi;
      }
      ((float4*)pw[w])[sigswz] = make_float4(pv[0], pv[1], pv[2], pv[3]);
      if (lane == 0) { float d = Br[0] - Bi[0]; pw[w][256] = d * d; }
    }
    __builtin_amdgcn_wave_barrier();

    // uniform mel gather: 8 x (global fbc quad, LDS pw quad); lane == mel.
    // 4 independent accumulators: serial fma chain 32 -> 8 deep.
    {
      const float4* pq = (const float4*)pw[w];
      const int la4 = la >> 2;
      float a0 = 0.0f, a1 = 0.0f, a2 = 0.0f, a3 = 0.0f;
#pragma unroll
      for (int jj = 0; jj < 8; ++jj) {
        float4 wq = fr4[jj];
        int q = PW_SWZ(la4 + jj);
        float4 p = pq[q];
        a0 = fmaf(wq.x, p.x, a0);
        a1 = fmaf(wq.y, p.y, a1);
        a2 = fmaf(wq.z, p.z, a2);
        a3 = fmaf(wq.w, p.w, a3);
      }
      float acc = (a0 + a1) + (a2 + a3);
      float lv = __logf(acc + LOG_GUARD_K);
      outm[lane][j] = lv;
      if (t0 + j < fl) { sm += lv; ssq = fmaf(lv, lv, ssq); }
    }
    __builtin_amdgcn_wave_barrier();
  }

  // park per-wave stats partials in the wave's OWN pw buffer (r3 race lesson)
  pw[w][lane] = sm;
  pw[w][64 + lane] = ssq;

  __syncthreads();

  // coalesced store: 8 consecutive t per mel row; 256 thr = 32 rows x 8 cols
#pragma unroll
  for (int p = 0; p < 2; ++p) {
    int row = p * 32 + (tid >> 3);
    int jj = tid & 7;
    int t = t0 + jj;
    if (t < T_FR)
      out[((size_t)(b << 6) + row) * T_PAD + t] = outm[row][jj];
  }

  // cross-wave reduce + fire-and-forget flush: 128 atomics/block, LAST ops
  if (tid < 64) {
    float s0 = pw[0][tid] + pw[1][tid] + pw[2][tid] + pw[3][tid];
    float q0 = pw[0][64 + tid] + pw[1][64 + tid] + pw[2][64 + tid] + pw[3][64 + tid];
    atomicAdd(&rsum[(b << 6) + tid], s0);
    atomicAdd(&rsumsq[(b << 6) + tid], q0);
  }
}

// K2: pure elementwise normalize (stats precomputed by K1) + feat_len write.
__global__ void __launch_bounds__(256) norm_elem_kernel(
    const int* __restrict__ seq_len, const float* __restrict__ rsum,
    const float* __restrict__ rsumsq, float* __restrict__ out,
    float* __restrict__ fl_out) {
  const int cidx = blockIdx.x * 256 + threadIdx.x;  // float4 chunk index
  const int bm = cidx / (T_PAD / 4);
  const int c4 = cidx - bm * (T_PAD / 4);
  const int b = bm >> 6;
  const int fl = seq_len[b] / HOP_K + 1;
  const float n = (float)fl;
  float s = rsum[bm], ssq = rsumsq[bm];
  float mean = s / n;
  float var = (ssq - s * mean) / (n - 1.0f);
  float istd = 1.0f / (sqrtf(var) + 1e-5f);
  float4* rowp = (float4*)(out + (size_t)bm * T_PAD);
  float4 v = rowp[c4];
  int t = 4 * c4;
  float4 o;
  o.x = (t < fl) ? (v.x - mean) * istd : 0.0f;
  o.y = (t + 1 < fl) ? (v.y - mean) * istd : 0.0f;
  o.z = (t + 2 < fl) ? (v.z - mean) * istd : 0.0f;
  o.w = (t + 3 < fl) ? (v.w - mean) * istd : 0.0f;
  rowp[c4] = o;
  if (blockIdx.x == 0 && threadIdx.x < 32)
    fl_out[threadIdx.x] = (float)(seq_len[threadIdx.x] / HOP_K + 1);
}

extern "C" void kernel_launch(void* const* d_in, const int* in_sizes, int n_in,
                              void* d_out, int out_size, void* d_ws, size_t ws_size,
                              hipStream_t stream) {
  const float* x = (const float*)d_in[0];
  const int* seq_len = (const int*)d_in[1];
  const float* window = (const float*)d_in[2];
  const float* fb = (const float*)d_in[3];
  float* out = (float*)d_out;
  float* fl_out = out + (size_t)32 * NMEL_K * T_PAD;
  float* fbc = (float*)d_ws;                          // 2048 floats
  int* loAl = (int*)((char*)d_ws + 8192);             // 64 ints
  float* rsum = (float*)((char*)d_ws + 8448);         // 2048 floats
  float* rsumsq = (float*)((char*)d_ws + 16640);      // 2048 floats

  prep_kernel<<<NMEL_K, 64, 0, stream>>>(fb, fbc, loAl, rsum, rsumsq);
  frame_fft_mel_kernel<<<32 * GROUPS, 256, 0, stream>>>(x, seq_len, window, fbc,
                                                        loAl, out, rsum, rsumsq);
  norm_elem_kernel<<<(32 * NMEL_K * T_PAD / 4) / 256, 256, 0, stream>>>(
      seq_len, rsum, rsumsq, out, fl_out);
}

// Round 13
// 126.304 us; speedup vs baseline: 1.1562x; 1.1562x over previous
//
#include <hip/hip_runtime.h>
#include <math.h>

#define L_IN 256000
#define T_FR 1601
#define T_PAD 1616
#define NMEL_K 64
#define F_BINS 257
#define HOP_K 160
#define PRE_E 0.97f
#define LOG_GUARD_K 5.9604644775390625e-08f  // 2^-24
#define FPB 16        // frames per block (r12 lesson: smaller FPB duplicates prologue)
#define CONC 4        // waves per block (r10 lesson: 512-thr caps VGPR@44)
#define GROUPS 101    // ceil(1601/16)
#define SPAN 2912     // 160*(FPB-1) + 512

typedef int v2i __attribute__((ext_vector_type(2)));

__device__ __forceinline__ float2 cmulf(float2 a, float2 b) {
  return make_float2(a.x * b.x - a.y * b.y, a.x * b.y + a.y * b.x);
}

// quad_perm DPP lane exchanges (VALU pipe — no DS cost).
__device__ __forceinline__ float dpp_xor1(float x) {
  return __int_as_float(__builtin_amdgcn_mov_dpp(__float_as_int(x), 0xB1, 0xF, 0xF, true));
}
__device__ __forceinline__ float dpp_xor2(float x) {
  return __int_as_float(__builtin_amdgcn_mov_dpp(__float_as_int(x), 0x4E, 0xF, 0xF, true));
}
// row_ror:8 == xor8 exchange. Verified exact in r6.
__device__ __forceinline__ float dpp_ror8(float x) {
  return __int_as_float(__builtin_amdgcn_mov_dpp(__float_as_int(x), 0x128, 0xF, 0xF, true));
}
// xor4 = row_half_mirror (0x141) then quad mirror (0x1B). Verified exact in r9.
__device__ __forceinline__ float dpp_hmir(float x) {
  return __int_as_float(__builtin_amdgcn_mov_dpp(__float_as_int(x), 0x141, 0xF, 0xF, true));
}
__device__ __forceinline__ float dpp_qmir(float x) {
  return __int_as_float(__builtin_amdgcn_mov_dpp(__float_as_int(x), 0x1B, 0xF, 0xF, true));
}
__device__ __forceinline__ float dpp_xor4(float x) { return dpp_qmir(dpp_hmir(x)); }

// gfx950 permlane swaps via the BUILTIN. Verified exact in r8.
__device__ __forceinline__ void lane_swap32(float v, float& lo, float& hi) {
  v2i r = __builtin_amdgcn_permlane32_swap(__float_as_int(v), __float_as_int(v),
                                           false, false);
  lo = __int_as_float(r.x);
  hi = __int_as_float(r.y);
}
__device__ __forceinline__ void lane_swap16(float v, float& lo, float& hi) {
  v2i r = __builtin_amdgcn_permlane16_swap(__float_as_int(v), __float_as_int(v),
                                           false, false);
  lo = __int_as_float(r.x);
  hi = __int_as_float(r.y);
}

// pw quad-slot swizzle. Verified r2..r12: conflicts 3.83M -> 1.19M, neutral math.
#define PW_SWZ(q) ((q) ^ (((q) >> 3) & 7))

// Prep: per-mel compact filterbank + aligned lo, zero stats accumulators, and
// (r13) block 0 precomputes the per-LANE constant table (identical for every
// K1 block — ~26 sincos/thread/block of K1 prologue moved here, computed ONCE
// with the exact same ops so values are bitwise identical).
__global__ void prep_kernel(const float* __restrict__ fb,
                            const float* __restrict__ window,
                            float* __restrict__ fbc,
                            int* __restrict__ loAl, float* __restrict__ rsum,
                            float* __restrict__ rsumsq,
                            float* __restrict__ lanetab) {
  const int m = blockIdx.x;
  const int t = threadIdx.x;
  if (t < 32) {
    rsum[m * 32 + t] = 0.0f;
    rsumsq[m * 32 + t] = 0.0f;
  }
  int first = 512, last = -1;
  for (int c = 0; c < 5; ++c) {
    int f = t + 64 * c;
    if (f < F_BINS) {
      float v = fb[m * F_BINS + f];
      if (v > 0.0f) { first = min(first, f); last = max(last, f); }
    }
  }
  for (int off = 32; off > 0; off >>= 1) {
    first = min(first, __shfl_xor(first, off));
    last = max(last, __shfl_xor(last, off));
  }
  int lo = (first <= last) ? first : 0;
  int lastv = (first <= last) ? last : 0;
  int la = lo & ~3;
  if (t == 0) loAl[m] = la;
  if (t < 32) {
    int f = la + t;
    float v = (f >= lo && f <= lastv && f < F_BINS) ? fb[m * F_BINS + f] : 0.0f;
    fbc[m * 32 + t] = v;
  }

  // ---- lane-constant table (block 0 only; thread t == lane t) ----
  if (m == 0) {
    const int l = t;
    float wr_[4], wi_[4];
#pragma unroll
    for (int q = 0; q < 4; ++q) {
      float2 wv = *(const float2*)(window + 2 * (l + 64 * q));
      wr_[q] = wv.x; wi_[q] = wv.y;
    }
    float2 tw1, tw2, tw3;
    {
      float a = -0.024543692606170259f * (float)l;  // -2*pi/256
      __sincosf(a, &tw1.y, &tw1.x);
      tw2 = cmulf(tw1, tw1);
      tw3 = cmulf(tw2, tw1);
    }
    float wcv[6], wsv[6], sgf[6];
#pragma unroll
    for (int i = 0; i < 6; ++i) {
      int H = 32 >> i;
      bool hi = (l & H) != 0;
      int p = l & (H - 1);
      float a = -3.14159265358979323846f * (float)p / (float)H;
      float s, c;
      __sincosf(a, &s, &c);
      wcv[i] = hi ? c : 1.0f;
      wsv[i] = hi ? s : 0.0f;
      sgf[i] = hi ? -1.0f : 1.0f;
    }
    const int sig = __builtin_bitreverse32(l) >> 26;
    float cu[4], su[4];
    {
      float a = -0.049087385212340519f * (float)sig;  // -pi/64
      float cb, sb;
      __sincosf(a, &sb, &cb);
      const float C[4] = {1.0f, 0.99992470183914454f, 0.99969881869620425f, 0.99932238458834954f};
      const float S[4] = {0.0f, 0.01227153828571993f, 0.02454122852291229f, 0.03680722294135883f};
#pragma unroll
      for (int r = 0; r < 4; ++r) {
        cu[r] = cb * C[r] + sb * S[r];
        su[r] = sb * C[r] - cb * S[r];
      }
    }
    float4* lt = (float4*)lanetab + l * 10;
    lt[0] = make_float4(wr_[0], wi_[0], wr_[1], wi_[1]);
    lt[1] = make_float4(wr_[2], wi_[2], wr_[3], wi_[3]);
    lt[2] = make_float4(tw1.x, tw1.y, tw2.x, tw2.y);
    lt[3] = make_float4(tw3.x, tw3.y, cu[0], su[0]);
    lt[4] = make_float4(cu[1], su[1], cu[2], su[2]);
    lt[5] = make_float4(cu[3], su[3], wcv[0], wsv[0]);
    lt[6] = make_float4(wcv[1], wsv[1], wcv[2], wsv[2]);
    lt[7] = make_float4(wcv[3], wsv[3], wcv[4], wsv[4]);
    lt[8] = make_float4(wcv[5], wsv[5], sgf[0], sgf[1]);
    lt[9] = make_float4(sgf[2], sgf[3], sgf[4], sgf[5]);
  }
}

// r11: sign-injected branch-free butterfly (verified): sg = hi?-1:+1,
// (wc,ws) = hi?twiddle:(1,0); u = fma(B,sg,t); out = u*W.
#define FFT_STAGE_X(I, PR, PI)                                 \
  {                                                            \
    const float sg__ = sgf[I], wc__ = wcv[I], ws__ = wsv[I];   \
    _Pragma("unroll")                                          \
    for (int r = 0; r < 4; ++r) {                              \
      float tr = (PR), ti = (PI);                              \
      float ur = fmaf(Br[r], sg__, tr);                        \
      float ui = fmaf(Bi[r], sg__, ti);                        \
      Br[r] = fmaf(-ws__, ui, ur * wc__);                      \
      Bi[r] = fmaf(ws__, ur, ui * wc__);                       \
    }                                                          \
  }

// Swap-based variant (stages H=32,16): u = fma(hi_val, sg, lo_val).
#define FFT_STAGE_XS(I, SWAPFN)                                \
  {                                                            \
    const float sg__ = sgf[I], wc__ = wcv[I], ws__ = wsv[I];   \
    _Pragma("unroll")                                          \
    for (int r = 0; r < 4; ++r) {                              \
      float lor, hir, loi, hii;                                \
      SWAPFN(Br[r], lor, hir);                                 \
      SWAPFN(Bi[r], loi, hii);                                 \
      float ur = fmaf(hir, sg__, lor);                         \
      float ui = fmaf(hii, sg__, loi);                         \
      Br[r] = fmaf(-ws__, ui, ur * wc__);                      \
      Bi[r] = fmaf(ws__, ur, ui * wc__);                       \
    }                                                          \
  }

// K1: 256 threads = 4 waves, 16 frames per block, one frame per wave per iter.
// r13: lane constants LOADED from the prep-computed table (10 float4/thread,
// L2-resident 10 KB) instead of ~26 sincos per thread per block. FFT math
// unchanged from r11 (verified). Lessons: r4 ILP spills; r10 512-thr caps
// VGPR; r12 small-FPB duplicates prologue.
__global__ void __launch_bounds__(256) frame_fft_mel_kernel(
    const float* __restrict__ x, const int* __restrict__ seq_len,
    const float* __restrict__ fbc,
    const int* __restrict__ loAl, const float* __restrict__ lanetab,
    float* __restrict__ out,
    float* __restrict__ rsum, float* __restrict__ rsumsq) {
  __shared__ __align__(16) float xs[SPAN];
  __shared__ __align__(16) float pw[CONC][288];
  __shared__ float outm[NMEL_K][FPB + 1];

  const int tid = threadIdx.x;
  const int w = tid >> 6;
  const int lane = tid & 63;
  const int b = blockIdx.x / GROUPS;
  const int g = blockIdx.x - b * GROUPS;
  const int t0 = g * FPB;
  const float* xb = x + (size_t)b * L_IN;
  const int base = t0 * HOP_K - 256;
  const int fl = seq_len[b] / HOP_K + 1;

  // issue lane-constant table loads early (overlap with staging)
  const float4* lt = (const float4*)lanetab + lane * 10;
  float4 c0 = lt[0], c1 = lt[1], c2 = lt[2], c3 = lt[3], c4 = lt[4];
  float4 c5 = lt[5], c6 = lt[6], c7 = lt[7], c8 = lt[8], c9 = lt[9];

  // stage input span: preemph (+ reflect on edge blocks)
  if (base >= 0 && base + SPAN <= L_IN) {
    const float4* xb4 = (const float4*)(xb + base);
    float4* xs4 = (float4*)xs;
    for (int s4 = tid; s4 < SPAN / 4; s4 += 256) {
      float4 cur = xb4[s4];
      float prev = xb[base + 4 * s4 - 1];
      float4 o;
      o.x = fmaf(-PRE_E, prev, cur.x);
      o.y = fmaf(-PRE_E, cur.x, cur.y);
      o.z = fmaf(-PRE_E, cur.y, cur.z);
      o.w = fmaf(-PRE_E, cur.z, cur.w);
      xs4[s4] = o;
    }
  } else {
    for (int n = tid; n < SPAN; n += 256) {
      int i = base + n;
      i = (i < 0) ? -i : i;
      i = (i >= L_IN) ? (2 * L_IN - 2 - i) : i;
      xs[n] = (i == 0) ? xb[0] : fmaf(-PRE_E, xb[i - 1], xb[i]);
    }
  }

  // zero pw tail once (gather overrun region 257..287 — never overwritten)
  if (lane >= 33 && lane < 64) pw[w][224 + lane] = 0.0f;  // 257..287

  // ---- unpack lane constants from table (registers; constant indices) ----
  const float wr[4] = {c0.x, c0.z, c1.x, c1.z};
  const float wi[4] = {c0.y, c0.w, c1.y, c1.w};
  const float2 tw1 = {c2.x, c2.y}, tw2 = {c2.z, c2.w}, tw3 = {c3.x, c3.y};
  const float cu[4] = {c3.z, c4.x, c4.z, c5.x};
  const float su[4] = {c3.w, c4.y, c4.w, c5.y};
  const float wcv[6] = {c5.z, c6.x, c6.z, c7.x, c7.z, c8.x};
  const float wsv[6] = {c5.w, c6.y, c6.w, c7.y, c7.w, c8.y};
  const float sgf[6] = {c8.z, c8.w, c9.x, c9.y, c9.z, c9.w};
  const int sig = __builtin_bitreverse32(lane) >> 26;  // bitrev6(lane)
  const int idx0 = __builtin_bitreverse32((64 - sig) & 63) >> 26;  // lane of Y0[(64-s)&63]
  const int la = loAl[lane];
  const float4* fr4 = (const float4*)fbc + lane * 8;
  const int sigswz = PW_SWZ(sig);  // hoisted swizzled write slot

  __syncthreads();

  float sm = 0.0f, ssq = 0.0f;  // per-(b, mel=lane) stats partials

  for (int c = 0; c < FPB / CONC; ++c) {
    const int j = c * CONC + w;
    const int off = j * HOP_K;

    float Br[4], Bi[4];
    {
      float zr[4], zi[4];
#pragma unroll
      for (int q = 0; q < 4; ++q) {
        float2 v = *(const float2*)(xs + off + 2 * (lane + 64 * q));
        zr[q] = v.x * wr[q];
        zi[q] = v.y * wi[q];
      }
      // FFT_4 over q (W4 = -i), then W256^{l*r} twiddle
      float e0r = zr[0] + zr[2], e0i = zi[0] + zi[2];
      float e1r = zr[1] + zr[3], e1i = zi[1] + zi[3];
      float d0r = zr[0] - zr[2], d0i = zi[0] - zi[2];
      float d1r = zr[1] - zr[3], d1i = zi[1] - zi[3];
      Br[0] = e0r + e1r; Bi[0] = e0i + e1i;
      float A2r = e0r - e1r, A2i = e0i - e1i;
      float A1r = d0r + d1i, A1i = d0i - d1r;
      float A3r = d0r - d1i, A3i = d0i + d1r;
      Br[1] = A1r * tw1.x - A1i * tw1.y; Bi[1] = A1r * tw1.y + A1i * tw1.x;
      Br[2] = A2r * tw2.x - A2i * tw2.y; Bi[2] = A2r * tw2.y + A2i * tw2.x;
      Br[3] = A3r * tw3.x - A3i * tw3.y; Bi[3] = A3r * tw3.y + A3i * tw3.x;
    }

    // FFT_64 across lanes: 6 DIF radix-2 stages, all VALU, all branch-free.
    FFT_STAGE_XS(0, lane_swap32);
    FFT_STAGE_XS(1, lane_swap16);
    FFT_STAGE_X(2, dpp_ror8(Br[r]), dpp_ror8(Bi[r]));
    FFT_STAGE_X(3, dpp_xor4(Br[r]), dpp_xor4(Bi[r]));
    FFT_STAGE_X(4, dpp_xor2(Br[r]), dpp_xor2(Bi[r]));
    // stage H=1: W = 1 identically — just the sign-injected add
    {
      const float sg5 = sgf[5];
#pragma unroll
      for (int r = 0; r < 4; ++r) {
        float tr = dpp_xor1(Br[r]), ti = dpp_xor1(Bi[r]);
        Br[r] = fmaf(Br[r], sg5, tr);
        Bi[r] = fmaf(Bi[r], sg5, ti);
      }
    }

    // packed-real unpack + power spectrum (k = 4*sig + r)
    {
      float q3r = __shfl_xor(Br[3], 63), q3i = __shfl_xor(Bi[3], 63);
      float q2r = __shfl_xor(Br[2], 63), q2i = __shfl_xor(Bi[2], 63);
      float q1r = __shfl_xor(Br[1], 63), q1i = __shfl_xor(Bi[1], 63);
      float q0r = __shfl(Br[0], idx0), q0i = __shfl(Bi[0], idx0);
      float qr[4] = {q0r, q3r, q2r, q1r};
      float qi_[4] = {q0i, q3i, q2i, q1i};
      float pv[4];
#pragma unroll
      for (int r = 0; r < 4; ++r) {
        float Er = 0.5f * (Br[r] + qr[r]);
        float Ei = 0.5f * (Bi[r] - qi_[r]);
        float Or = 0.5f * (Bi[r] + qi_[r]);
        float Oi = 0.5f * (qr[r] - Br[r]);
        float Xr = Er + cu[r] * Or - su[r] * Oi;
        float Xi = Ei + cu[r] * Oi + su[r] * Or;
        pv[r] = Xr * Xr + Xi * Xi;
      }
      ((float4*)pw[w])[sigswz] = make_float4(pv[0], pv[1], pv[2], pv[3]);
      if (lane == 0) { float d = Br[0] - Bi[0]; pw[w][256] = d * d; }
    }
    __builtin_amdgcn_wave_barrier();

    // uniform mel gather: 8 x (global fbc quad, LDS pw quad); lane == mel.
    // 4 independent accumulators: serial fma chain 32 -> 8 deep.
    {
      const float4* pq = (const float4*)pw[w];
      const int la4 = la >> 2;
      float a0 = 0.0f, a1 = 0.0f, a2 = 0.0f, a3 = 0.0f;
#pragma unroll
      for (int jj = 0; jj < 8; ++jj) {
        float4 wq = fr4[jj];
        int q = PW_SWZ(la4 + jj);
        float4 p = pq[q];
        a0 = fmaf(wq.x, p.x, a0);
        a1 = fmaf(wq.y, p.y, a1);
        a2 = fmaf(wq.z, p.z, a2);
        a3 = fmaf(wq.w, p.w, a3);
      }
      float acc = (a0 + a1) + (a2 + a3);
      float lv = __logf(acc + LOG_GUARD_K);
      outm[lane][j] = lv;
      if (t0 + j < fl) { sm += lv; ssq = fmaf(lv, lv, ssq); }
    }
    __builtin_amdgcn_wave_barrier();
  }

  // park per-wave stats partials in the wave's OWN pw buffer (r3 race lesson)
  pw[w][lane] = sm;
  pw[w][64 + lane] = ssq;

  __syncthreads();

  // coalesced store: 16 consecutive t per mel row
#pragma unroll
  for (int p = 0; p < 4; ++p) {
    int row = p * 16 + (tid >> 4);
    int jj = tid & 15;
    int t = t0 + jj;
    if (t < T_FR)
      out[((size_t)(b << 6) + row) * T_PAD + t] = outm[row][jj];
  }

  // cross-wave reduce + fire-and-forget flush: 128 atomics/block, LAST ops
  if (tid < 64) {
    float s0 = pw[0][tid] + pw[1][tid] + pw[2][tid] + pw[3][tid];
    float q0 = pw[0][64 + tid] + pw[1][64 + tid] + pw[2][64 + tid] + pw[3][64 + tid];
    atomicAdd(&rsum[(b << 6) + tid], s0);
    atomicAdd(&rsumsq[(b << 6) + tid], q0);
  }
}

// K2: pure elementwise normalize (stats precomputed by K1) + feat_len write.
__global__ void __launch_bounds__(256) norm_elem_kernel(
    const int* __restrict__ seq_len, const float* __restrict__ rsum,
    const float* __restrict__ rsumsq, float* __restrict__ out,
    float* __restrict__ fl_out) {
  const int cidx = blockIdx.x * 256 + threadIdx.x;  // float4 chunk index
  const int bm = cidx / (T_PAD / 4);
  const int c4 = cidx - bm * (T_PAD / 4);
  const int b = bm >> 6;
  const int fl = seq_len[b] / HOP_K + 1;
  const float n = (float)fl;
  float s = rsum[bm], ssq = rsumsq[bm];
  float mean = s / n;
  float var = (ssq - s * mean) / (n - 1.0f);
  float istd = 1.0f / (sqrtf(var) + 1e-5f);
  float4* rowp = (float4*)(out + (size_t)bm * T_PAD);
  float4 v = rowp[c4];
  int t = 4 * c4;
  float4 o;
  o.x = (t < fl) ? (v.x - mean) * istd : 0.0f;
  o.y = (t + 1 < fl) ? (v.y - mean) * istd : 0.0f;
  o.z = (t + 2 < fl) ? (v.z - mean) * istd : 0.0f;
  o.w = (t + 3 < fl) ? (v.w - mean) * istd : 0.0f;
  rowp[c4] = o;
  if (blockIdx.x == 0 && threadIdx.x < 32)
    fl_out[threadIdx.x] = (float)(seq_len[threadIdx.x] / HOP_K + 1);
}

extern "C" void kernel_launch(void* const* d_in, const int* in_sizes, int n_in,
                              void* d_out, int out_size, void* d_ws, size_t ws_size,
                              hipStream_t stream) {
  const float* x = (const float*)d_in[0];
  const int* seq_len = (const int*)d_in[1];
  const float* window = (const float*)d_in[2];
  const float* fb = (const float*)d_in[3];
  float* out = (float*)d_out;
  float* fl_out = out + (size_t)32 * NMEL_K * T_PAD;
  float* fbc = (float*)d_ws;                          // 2048 floats     @ 0
  int* loAl = (int*)((char*)d_ws + 8192);             // 64 ints         @ 8192
  float* rsum = (float*)((char*)d_ws + 8448);         // 2048 floats     @ 8448
  float* rsumsq = (float*)((char*)d_ws + 16640);      // 2048 floats     @ 16640
  float* lanetab = (float*)((char*)d_ws + 24832);     // 64*40 floats    @ 24832

  prep_kernel<<<NMEL_K, 64, 0, stream>>>(fb, window, fbc, loAl, rsum, rsumsq,
                                         lanetab);
  frame_fft_mel_kernel<<<32 * GROUPS, 256, 0, stream>>>(x, seq_len, fbc, loAl,
                                                        lanetab, out, rsum,
                                                        rsumsq);
  norm_elem_kernel<<<(32 * NMEL_K * T_PAD / 4) / 256, 256, 0, stream>>>(
      seq_len, rsum, rsumsq, out, fl_out);
}

// Round 14
// 122.833 us; speedup vs baseline: 1.1889x; 1.0283x over previous
//
#include <hip/hip_runtime.h>
#include <math.h>

#define L_IN 256000
#define T_FR 1601
#define T_PAD 1616
#define NMEL_K 64
#define F_BINS 257
#define HOP_K 160
#define PRE_E 0.97f
#define LOG_GUARD_K 5.9604644775390625e-08f  // 2^-24
#define FPB 16        // frames per block
#define CONC 4        // one frame per wave
#define GROUPS 101    // ceil(1601/16)
#define SPAN 2912     // 160*(FPB-1) + 512

__device__ __forceinline__ float2 cmulf(float2 a, float2 b) {
  return make_float2(a.x * b.x - a.y * b.y, a.x * b.y + a.y * b.x);
}

// quad_perm DPP lane exchanges (VALU pipe — no DS cost).
// xor1: perm [1,0,3,2] = 0xB1; xor2: perm [2,3,0,1] = 0x4E.
__device__ __forceinline__ float dpp_xor1(float x) {
  return __int_as_float(__builtin_amdgcn_mov_dpp(__float_as_int(x), 0xB1, 0xF, 0xF, true));
}
__device__ __forceinline__ float dpp_xor2(float x) {
  return __int_as_float(__builtin_amdgcn_mov_dpp(__float_as_int(x), 0x4E, 0xF, 0xF, true));
}
// row_ror:8 (ctrl 0x120+8): rotate within each 16-lane row by 8 == xor8 exchange
// ((i+8) mod 16 == i^8 either direction). Verified exact in r6.
__device__ __forceinline__ float dpp_ror8(float x) {
  return __int_as_float(__builtin_amdgcn_mov_dpp(__float_as_int(x), 0x128, 0xF, 0xF, true));
}

// pw quad-slot swizzle: spread (slot mod 8) bank groups using slot high bits.
// Bijective on 0..63; identity on 64..71 (Nyquist + zero tail).
// Verified r2..r13: bank-conflict cycles 3.83M -> 1.19M, numerically neutral.
#define PW_SWZ(q) ((q) ^ (((q) >> 3) & 7))

// Prep: per-mel compact filterbank (32 wide, 16B-aligned, zero-padded) + aligned lo,
// and zero the stats accumulators (ws is poisoned 0xAA before every launch).
__global__ void prep_kernel(const float* __restrict__ fb, float* __restrict__ fbc,
                            int* __restrict__ loAl, float* __restrict__ rsum,
                            float* __restrict__ rsumsq) {
  const int m = blockIdx.x;
  const int t = threadIdx.x;
  if (t < 32) {  // zero stats: 64 blocks x 32 = 2048 each
    rsum[m * 32 + t] = 0.0f;
    rsumsq[m * 32 + t] = 0.0f;
  }
  int first = 512, last = -1;
  for (int c = 0; c < 5; ++c) {
    int f = t + 64 * c;
    if (f < F_BINS) {
      float v = fb[m * F_BINS + f];
      if (v > 0.0f) { first = min(first, f); last = max(last, f); }
    }
  }
  for (int off = 32; off > 0; off >>= 1) {
    first = min(first, __shfl_xor(first, off));
    last = max(last, __shfl_xor(last, off));
  }
  int lo = (first <= last) ? first : 0;
  int lastv = (first <= last) ? last : 0;
  int la = lo & ~3;
  if (t == 0) loAl[m] = la;
  if (t < 32) {
    int f = la + t;
    float v = (f >= lo && f <= lastv && f < F_BINS) ? fb[m * F_BINS + f] : 0.0f;
    fbc[m * 32 + t] = v;
  }
}

// Butterfly stage macro: partner expressions are per-register r.
#define FFT_STAGE(I, PR, PI)                                        \
  {                                                                 \
    const int H__ = 32 >> (I);                                      \
    const bool hi__ = (lane & H__) != 0;                            \
    const float cc__ = stc[I], ss__ = sts[I];                       \
    _Pragma("unroll")                                               \
    for (int r = 0; r < 4; ++r) {                                   \
      float tr = (PR), ti = (PI);                                   \
      float sr = Br[r] + tr, si = Bi[r] + ti;                       \
      float dr = tr - Br[r], di = ti - Bi[r];                       \
      float pr = dr * cc__ - di * ss__, pi = dr * ss__ + di * cc__; \
      Br[r] = hi__ ? pr : sr;                                       \
      Bi[r] = hi__ ? pi : si;                                       \
    }                                                               \
  }

// K1: 256 threads = 4 waves, 16 frames per block, one frame per wave per iter.
// Register 4-step FFT: stages H=32,16,4 via __shfl_xor (DS bpermute),
// H=8 via DPP row_ror:8, H=2,1 via DPP quad_perm (VALU pipe).
// Sparse mel, logmel, fused stats with atomics.
// === SESSION-BEST VARIANT (r6: 122.0 µs total, K1 47.3 µs) ===
// Post-r6 variants (permlane swaps r8, all-VALU exchanges r9, sign-injection
// r11, lane-const table r13) all measured within noise or worse; structural
// retries (2-frame ILP r4, 512-thr r10, FPB=8 r12) regressed. K1 ~47 µs is
// this decomposition's floor: VALUBusy ~60%, remainder is dependency-stall
// slack that six orthogonal attacks failed to move.
__global__ void __launch_bounds__(256) frame_fft_mel_kernel(
    const float* __restrict__ x, const int* __restrict__ seq_len,
    const float* __restrict__ window, const float* __restrict__ fbc,
    const int* __restrict__ loAl, float* __restrict__ out,
    float* __restrict__ rsum, float* __restrict__ rsumsq) {
  __shared__ __align__(16) float xs[SPAN];
  __shared__ __align__(16) float pw[CONC][288];
  __shared__ float outm[NMEL_K][FPB + 1];

  const int tid = threadIdx.x;
  const int w = tid >> 6;
  const int lane = tid & 63;
  const int b = blockIdx.x / GROUPS;
  const int g = blockIdx.x - b * GROUPS;
  const int t0 = g * FPB;
  const float* xb = x + (size_t)b * L_IN;
  const int base = t0 * HOP_K - 256;
  const int fl = seq_len[b] / HOP_K + 1;

  // stage input span: preemph (+ reflect on edge blocks)
  if (base >= 0 && base + SPAN <= L_IN) {
    // fast path: float4 interior (base is a multiple of 4 for g>0)
    const float4* xb4 = (const float4*)(xb + base);
    float4* xs4 = (float4*)xs;
    for (int s4 = tid; s4 < SPAN / 4; s4 += 256) {
      float4 cur = xb4[s4];
      float prev = xb[base + 4 * s4 - 1];
      float4 o;
      o.x = fmaf(-PRE_E, prev, cur.x);
      o.y = fmaf(-PRE_E, cur.x, cur.y);
      o.z = fmaf(-PRE_E, cur.y, cur.z);
      o.w = fmaf(-PRE_E, cur.z, cur.w);
      xs4[s4] = o;
    }
  } else {
    for (int n = tid; n < SPAN; n += 256) {
      int i = base + n;
      i = (i < 0) ? -i : i;
      i = (i >= L_IN) ? (2 * L_IN - 2 - i) : i;
      xs[n] = (i == 0) ? xb[0] : fmaf(-PRE_E, xb[i - 1], xb[i]);
    }
  }

  // zero pw tail once (gather overrun region 257..287 — never overwritten)
  if (lane >= 33 && lane < 64) pw[w][224 + lane] = 0.0f;  // 257..287

  // ---- per-lane frame-invariant constants (all hoisted) ----
  const int sig = __builtin_bitreverse32(lane) >> 26;  // bitrev6(lane)
  float wr[4], wi[4];
#pragma unroll
  for (int q = 0; q < 4; ++q) {
    float2 wv = *(const float2*)(window + 2 * (lane + 64 * q));
    wr[q] = wv.x; wi[q] = wv.y;
  }
  float2 tw1, tw2, tw3;  // W256^(l*r)
  {
    float a = -0.024543692606170259f * (float)lane;  // -2*pi/256
    __sincosf(a, &tw1.y, &tw1.x);
    tw2 = cmulf(tw1, tw1);
    tw3 = cmulf(tw2, tw1);
  }
  float stc[6], sts[6];  // DIF stage twiddles W_{2H}^{lane&(H-1)}
#pragma unroll
  for (int i = 0; i < 6; ++i) {
    int H = 32 >> i;
    int p = lane & (H - 1);
    float a = -3.14159265358979323846f * (float)p / (float)H;
    __sincosf(a, &sts[i], &stc[i]);
  }
  float cu[4], su[4];  // unpack twiddle e^{-i*pi*(4*sig+r)/256}
  {
    float a = -0.049087385212340519f * (float)sig;  // -pi/64
    float cb, sb;
    __sincosf(a, &sb, &cb);
    const float C[4] = {1.0f, 0.99992470183914454f, 0.99969881869620425f, 0.99932238458834954f};
    const float S[4] = {0.0f, 0.01227153828571993f, 0.02454122852291229f, 0.03680722294135883f};
#pragma unroll
    for (int r = 0; r < 4; ++r) {
      cu[r] = cb * C[r] + sb * S[r];
      su[r] = sb * C[r] - cb * S[r];
    }
  }
  const int idx0 = __builtin_bitreverse32((64 - sig) & 63) >> 26;  // lane of Y0[(64-s)&63]
  const int la = loAl[lane];
  const float4* fr4 = (const float4*)fbc + lane * 8;
  const int sigswz = PW_SWZ(sig);  // hoisted swizzled write slot

  __syncthreads();

  float sm = 0.0f, ssq = 0.0f;  // per-(b, mel=lane) stats partials

  for (int c = 0; c < FPB / CONC; ++c) {
    const int j = c * CONC + w;
    const int off = j * HOP_K;

    float Br[4], Bi[4];
    {
      float zr[4], zi[4];
#pragma unroll
      for (int q = 0; q < 4; ++q) {
        float2 v = *(const float2*)(xs + off + 2 * (lane + 64 * q));
        zr[q] = v.x * wr[q];
        zi[q] = v.y * wi[q];
      }
      // FFT_4 over q (W4 = -i), then W256^{l*r} twiddle
      float e0r = zr[0] + zr[2], e0i = zi[0] + zi[2];
      float e1r = zr[1] + zr[3], e1i = zi[1] + zi[3];
      float d0r = zr[0] - zr[2], d0i = zi[0] - zi[2];
      float d1r = zr[1] - zr[3], d1i = zi[1] - zi[3];
      Br[0] = e0r + e1r; Bi[0] = e0i + e1i;
      float A2r = e0r - e1r, A2i = e0i - e1i;
      float A1r = d0r + d1i, A1i = d0i - d1r;
      float A3r = d0r - d1i, A3i = d0i + d1r;
      Br[1] = A1r * tw1.x - A1i * tw1.y; Bi[1] = A1r * tw1.y + A1i * tw1.x;
      Br[2] = A2r * tw2.x - A2i * tw2.y; Bi[2] = A2r * tw2.y + A2i * tw2.x;
      Br[3] = A3r * tw3.x - A3i * tw3.y; Bi[3] = A3r * tw3.y + A3i * tw3.x;
    }

    // FFT_64 across lanes: 6 DIF radix-2 stages.
    // H=32,16,4 via shfl_xor (DS bpermute); H=8 via DPP row_ror:8 (VALU);
    // H=2,1 via DPP quad_perm (VALU).
    FFT_STAGE(0, __shfl_xor(Br[r], 32), __shfl_xor(Bi[r], 32));
    FFT_STAGE(1, __shfl_xor(Br[r], 16), __shfl_xor(Bi[r], 16));
    FFT_STAGE(2, dpp_ror8(Br[r]), dpp_ror8(Bi[r]));
    FFT_STAGE(3, __shfl_xor(Br[r], 4), __shfl_xor(Bi[r], 4));
    FFT_STAGE(4, dpp_xor2(Br[r]), dpp_xor2(Bi[r]));
    FFT_STAGE(5, dpp_xor1(Br[r]), dpp_xor1(Bi[r]));

    // packed-real unpack + power spectrum (k = 4*sig + r)
    {
      float q3r = __shfl_xor(Br[3], 63), q3i = __shfl_xor(Bi[3], 63);
      float q2r = __shfl_xor(Br[2], 63), q2i = __shfl_xor(Bi[2], 63);
      float q1r = __shfl_xor(Br[1], 63), q1i = __shfl_xor(Bi[1], 63);
      float q0r = __shfl(Br[0], idx0), q0i = __shfl(Bi[0], idx0);
      float qr[4] = {q0r, q3r, q2r, q1r};
      float qi_[4] = {q0i, q3i, q2i, q1i};
      float pv[4];
#pragma unroll
      for (int r = 0; r < 4; ++r) {
        float Er = 0.5f * (Br[r] + qr[r]);
        float Ei = 0.5f * (Bi[r] - qi_[r]);
        float Or = 0.5f * (Bi[r] + qi_[r]);
        float Oi = 0.5f * (qr[r] - Br[r]);
        float Xr = Er + cu[r] * Or - su[r] * Oi;
        float Xi = Ei + cu[r] * Oi + su[r] * Or;
        pv[r] = Xr * Xr + Xi * Xi;
      }
      ((float4*)pw[w])[sigswz] = make_float4(pv[0], pv[1], pv[2], pv[3]);
      if (lane == 0) { float d = Br[0] - Bi[0]; pw[w][256] = d * d; }
    }
    __builtin_amdgcn_wave_barrier();

    // uniform mel gather: 8 x (global fbc quad, LDS pw quad); lane == mel
    {
      const float4* pq = (const float4*)pw[w];
      const int la4 = la >> 2;
      float acc = 0.0f;
#pragma unroll
      for (int jj = 0; jj < 8; ++jj) {
        float4 wq = fr4[jj];
        int q = PW_SWZ(la4 + jj);
        float4 p = pq[q];
        acc = fmaf(wq.x, p.x, acc);
        acc = fmaf(wq.y, p.y, acc);
        acc = fmaf(wq.z, p.z, acc);
        acc = fmaf(wq.w, p.w, acc);
      }
      float lv = __logf(acc + LOG_GUARD_K);
      outm[lane][j] = lv;
      if (t0 + j < fl) { sm += lv; ssq = fmaf(lv, lv, ssq); }
    }
    __builtin_amdgcn_wave_barrier();
  }

  // park per-wave stats partials in pw scratch (mel loop done, pw is free;
  // wave w owns pw[w] — safe)
  pw[w][lane] = sm;
  pw[w][64 + lane] = ssq;

  __syncthreads();

  // coalesced store: 16 consecutive t per mel row
#pragma unroll
  for (int p = 0; p < 4; ++p) {
    int row = p * 16 + (tid >> 4);
    int jj = tid & 15;
    int t = t0 + jj;
    if (t < T_FR)
      out[((size_t)(b << 6) + row) * T_PAD + t] = outm[row][jj];
  }

  // cross-wave reduce + fire-and-forget flush: 128 atomics/block, LAST ops,
  // no trailing barrier (drain overlaps with block retirement)
  if (tid < 64) {
    float s0 = pw[0][tid] + pw[1][tid] + pw[2][tid] + pw[3][tid];
    float q0 = pw[0][64 + tid] + pw[1][64 + tid] + pw[2][64 + tid] + pw[3][64 + tid];
    atomicAdd(&rsum[(b << 6) + tid], s0);
    atomicAdd(&rsumsq[(b << 6) + tid], q0);
  }
}

// K2: pure elementwise normalize (stats precomputed by K1) + feat_len write.
__global__ void __launch_bounds__(256) norm_elem_kernel(
    const int* __restrict__ seq_len, const float* __restrict__ rsum,
    const float* __restrict__ rsumsq, float* __restrict__ out,
    float* __restrict__ fl_out) {
  const int cidx = blockIdx.x * 256 + threadIdx.x;  // float4 chunk index
  const int bm = cidx / (T_PAD / 4);
  const int c4 = cidx - bm * (T_PAD / 4);
  const int b = bm >> 6;
  const int fl = seq_len[b] / HOP_K + 1;
  const float n = (float)fl;
  float s = rsum[bm], ssq = rsumsq[bm];
  float mean = s / n;
  float var = (ssq - s * mean) / (n - 1.0f);
  float istd = 1.0f / (sqrtf(var) + 1e-5f);
  float4* rowp = (float4*)(out + (size_t)bm * T_PAD);
  float4 v = rowp[c4];
  int t = 4 * c4;
  float4 o;
  o.x = (t < fl) ? (v.x - mean) * istd : 0.0f;
  o.y = (t + 1 < fl) ? (v.y - mean) * istd : 0.0f;
  o.z = (t + 2 < fl) ? (v.z - mean) * istd : 0.0f;
  o.w = (t + 3 < fl) ? (v.w - mean) * istd : 0.0f;
  rowp[c4] = o;
  if (blockIdx.x == 0 && threadIdx.x < 32)
    fl_out[threadIdx.x] = (float)(seq_len[threadIdx.x] / HOP_K + 1);
}

extern "C" void kernel_launch(void* const* d_in, const int* in_sizes, int n_in,
                              void* d_out, int out_size, void* d_ws, size_t ws_size,
                              hipStream_t stream) {
  const float* x = (const float*)d_in[0];
  const int* seq_len = (const int*)d_in[1];
  const float* window = (const float*)d_in[2];
  const float* fb = (const float*)d_in[3];
  float* out = (float*)d_out;
  float* fl_out = out + (size_t)32 * NMEL_K * T_PAD;
  float* fbc = (float*)d_ws;                          // 2048 floats
  int* loAl = (int*)((char*)d_ws + 8192);             // 64 ints
  float* rsum = (float*)((char*)d_ws + 8448);         // 2048 floats
  float* rsumsq = (float*)((char*)d_ws + 16640);      // 2048 floats

  prep_kernel<<<NMEL_K, 64, 0, stream>>>(fb, fbc, loAl, rsum, rsumsq);
  frame_fft_mel_kernel<<<32 * GROUPS, 256, 0, stream>>>(x, seq_len, window, fbc,
                                                        loAl, out, rsum, rsumsq);
  norm_elem_kernel<<<(32 * NMEL_K * T_PAD / 4) / 256, 256, 0, stream>>>(
      seq_len, rsum, rsumsq, out, fl_out);
}